// Round 9
// baseline (73.849 us; speedup 1.0000x reference)
//
#include <hip/hip_runtime.h>
#include <hip/hip_fp16.h>

#define VOCAB 100000
#define EMB   20
#define HID   10
#define SEQ   100
#define NLAB  15
#define BATCH 16384
#define GATES 40
#define PROWH 40  // halfs/row, slot = u*4+G: [u0..7 quads @ 4*sub8][u8 ifco][u9 ifco]

__device__ __forceinline__ float exp2_f(float x){ float r; asm("v_exp_f32 %0, %1" : "=v"(r) : "v"(x)); return r; }
__device__ __forceinline__ float rcp_f(float x){ float r; asm("v_rcp_f32 %0, %1" : "=v"(r) : "v"(x)); return r; }

// Gate scales folded into P/Wh: sigmoid(x)=rcp(1+exp2(-log2e*x)),
// tanh(x)=(1-E)/(1+E), E=exp2(-2log2e*x). c-gate scale -2log2e, others -log2e.
__device__ __host__ __forceinline__ constexpr float gscale(int G){
  return (G == 2) ? -2.885390081777927f : -1.442695040888963f;
}

template<int CTRL>
__device__ __forceinline__ float qb(float x){
  return __int_as_float(__builtin_amdgcn_mov_dpp(__float_as_int(x), CTRL, 0xF, 0xF, true));
}

// -------- P = fp16( (embed @ Wx + b) * gate_scale ), row = 40 halfs, slot = u*4+G (r8, proven)
__global__ __launch_bounds__(256)
void proj_kernel_h(const float* __restrict__ emb, const float* __restrict__ Wx,
                   const float* __restrict__ bias, __half* __restrict__ P)
{
  __shared__ float Wxl[EMB * GATES];   // [k][slot], slot = u*4+G
  __shared__ float bl[GATES];
  const int tid = threadIdx.x;
  for (int i = tid; i < EMB * GATES; i += 256) {
    int k = i / GATES, slot = i - k * GATES;
    int u = slot >> 2, G = slot & 3;
    Wxl[i] = Wx[k * GATES + G * HID + u] * gscale(G);
  }
  if (tid < GATES) {
    int u = tid >> 2, G = tid & 3;
    bl[tid] = bias[G * HID + u] * gscale(G);
  }
  __syncthreads();

  const int v   = blockIdx.x * 32 + (tid >> 3);
  const int sub = tid & 7;
  if (v >= VOCAB) return;

  const float4* er = (const float4*)(emb + (size_t)v * EMB);
  float4 e0 = er[0], e1 = er[1], e2 = er[2], e3 = er[3], e4 = er[4];
  float e[EMB] = {e0.x,e0.y,e0.z,e0.w, e1.x,e1.y,e1.z,e1.w, e2.x,e2.y,e2.z,e2.w,
                  e3.x,e3.y,e3.z,e3.w, e4.x,e4.y,e4.z,e4.w};

  int sl[5] = {4*sub, 4*sub+1, 4*sub+2, 4*sub+3, 32+sub};
  float acc[5];
  #pragma unroll
  for (int c = 0; c < 5; ++c) acc[c] = bl[sl[c]];
  #pragma unroll
  for (int k = 0; k < EMB; ++k)
    #pragma unroll
    for (int c = 0; c < 5; ++c)
      acc[c] = fmaf(e[k], Wxl[k * GATES + sl[c]], acc[c]);

  union { __half h[4]; uint2 u2; } um;
  #pragma unroll
  for (int c = 0; c < 4; ++c) um.h[c] = __float2half(acc[c]);
  *(uint2*)(P + (size_t)v * PROWH + 4 * sub) = um.u2;
  P[(size_t)v * PROWH + 32 + sub] = __float2half(acc[4]);
}

// -------- 16-lane-per-element LSTM: f32 recurrence, fp16 P rows, LDS z/h shuffle.
// Lane L owns z-slots {2L, 2L+1} and (L<8) slot 32+L. Lane u<10 activates unit u
// (lanes 10-15 duplicate unit 9). z/h exchanged through per-element LDS rows.
__global__ __launch_bounds__(256, 4)
void rnn16_kernel(const int* __restrict__ x, const __half* __restrict__ P,
                  const float* __restrict__ Wh, const float* __restrict__ Wd,
                  const float* __restrict__ bd, float* __restrict__ out)
{
  __shared__ int xs[16 * SEQ];
  __shared__ __align__(16) float zbuf[16][48];   // 40 slots + 8 pad (lanes 8-15's dummy 3rd slot)
  __shared__ __align__(16) float hbuf[16][16];   // 10 h + pad

  const int tid = threadIdx.x;
  const int grp = tid >> 4;        // local element 0..15 (4 per wave -> wave-private rows)
  const int L   = tid & 15;
  const int b0  = blockIdx.x * 16;

  for (int i = tid; i < 16 * SEQ; i += 256) xs[i] = x[(size_t)b0 * SEQ + i];

  // f32 recurrent weights: 30 per lane (information floor at 16 lanes)
  const int s0 = 2 * L, s1 = 2 * L + 1;
  const int G0 = s0 & 3, u0 = s0 >> 2;
  const int G1 = s1 & 3, u1 = s1 >> 2;
  const int Ge = L & 3,  ue = 8 + (L >> 2);
  float wm0[HID], wm1[HID], we[HID];
  #pragma unroll
  for (int k = 0; k < HID; ++k) {
    wm0[k] = Wh[k * GATES + G0 * HID + u0] * gscale(G0);
    wm1[k] = Wh[k * GATES + G1 * HID + u1] * gscale(G1);
    we[k]  = (L < 8) ? Wh[k * GATES + Ge * HID + ue] * gscale(Ge) : 0.f;
  }

  __syncthreads();

  float* zrow = zbuf[grp];
  float* hrow = hbuf[grp];
  const int* xrow = xs + grp * SEQ;
  const int ug = (L < 9) ? L : 9;          // activated unit (dupes for L>=10)

  float cm = 0.f;
  float h[HID];
  #pragma unroll
  for (int k = 0; k < HID; ++k) h[k] = 0.f;

  unsigned mA, mB, mC; __half eA, eB, eC;
  auto ldrow = [&](unsigned& m, __half& ex, int t) {
    int tt = t < SEQ ? t : SEQ - 1;
    const __half* rp = P + (size_t)xrow[tt] * PROWH;
    m  = *(const unsigned*)(rp + 2 * L);   // slots 2L, 2L+1
    ex = rp[32 + (L & 7)];                 // slot 32+L for L<8; harmless dup for L>=8
  };
  ldrow(mA, eA, 0); ldrow(mB, eB, 1); ldrow(mC, eC, 2);

  auto step = [&](unsigned& m, __half& ex, int t) {
    float2 a = __half22float2(*(const __half2*)&m);
    float z0 = a.x, z1 = a.y;
    float z5 = __half2float(ex);
    ldrow(m, ex, t + 3);                   // depth-3 prefetch

    #pragma unroll
    for (int k = 0; k < HID; ++k) {
      z0 = fmaf(h[k], wm0[k], z0);
      z1 = fmaf(h[k], wm1[k], z1);
      z5 = fmaf(h[k], we[k],  z5);
    }

    // scatter z to the element's LDS row (pads 40..47 absorb lanes 8-15's z5)
    zrow[2 * L]     = z0;
    zrow[2 * L + 1] = z1;
    zrow[32 + L]    = z5;

    // gather this lane's unit gates (i,f,c,o) and run ONE activation chain
    const float4 g = *(const float4*)(zrow + 4 * ug);
    float hm;
    {
      float Ei = exp2_f(g.x);
      float Ef = exp2_f(g.y);
      float Ec = exp2_f(fminf(g.z, 60.f));
      float Eo = exp2_f(g.w);
      float f  = rcp_f(1.f + Ef);
      float ig = (1.f - Ec) * rcp_f((1.f + Ei) * (1.f + Ec));
      cm = fmaf(f, cm, ig);                                   // c = f*c + i*tanh(c~)
      float Et = exp2_f(fminf(-2.885390081777927f * cm, 60.f));
      hm = (1.f - Et) * rcp_f((1.f + Eo) * (1.f + Et));       // h = o*tanh(c)
    }

    hrow[L] = hm;                          // lanes 10-15 write dup h9 to pad slots
    const float4 h03 = *(const float4*)(hrow);
    const float4 h47 = *(const float4*)(hrow + 4);
    const float2 h89 = *(const float2*)(hrow + 8);
    h[0] = h03.x; h[1] = h03.y; h[2] = h03.z; h[3] = h03.w;
    h[4] = h47.x; h[5] = h47.y; h[6] = h47.z; h[7] = h47.w;
    h[8] = h89.x; h[9] = h89.y;
  };

  #pragma unroll 1
  for (int t = 0; t < SEQ - 1; t += 3) {   // 33 triples: t = 0..98
    step(mA, eA, t);
    step(mB, eB, t + 1);
    step(mC, eC, t + 2);
  }
  step(mA, eA, SEQ - 1);                   // t = 99

  // dense head: lane L computes logit L
  if (L < NLAB) {
    float acc = bd[L];
    #pragma unroll
    for (int k = 0; k < HID; ++k)
      acc = fmaf(h[k], Wd[k * NLAB + L], acc);
    out[(size_t)(b0 + grp) * NLAB + L] = acc;
  }
}

// -------- fallback (ws too small for P): 4-lane on-the-fly f32 path (proven)
__global__ __launch_bounds__(256, 1)
void rnn_kernel_fb(const int* __restrict__ x, const float* __restrict__ emb,
                   const float* __restrict__ Wx, const float* __restrict__ Wh,
                   const float* __restrict__ bias, const float* __restrict__ Wd,
                   const float* __restrict__ bd, float* __restrict__ out)
{
  __shared__ int   xs[64 * SEQ];
  __shared__ float Wxl[EMB * 48];
  __shared__ float bls[48];
  const int tid = threadIdx.x, lb = tid >> 2, sub = tid & 3, b0 = blockIdx.x * 64;
  for (int i = tid; i < 64 * SEQ; i += 256) xs[i] = x[(size_t)b0 * SEQ + i];
  for (int i = tid; i < EMB * 48; i += 256) {
    int k = i / 48, slot = i - k * 48;
    int sb2 = slot / 12, r = slot - sb2 * 12, G = r / 3, s = r - G * 3, u = s * 4 + sb2;
    Wxl[i] = (u < HID) ? Wx[k * GATES + G * HID + u] * gscale(G) : 0.f;
  }
  if (tid < 48) {
    int slot = tid, sb2 = slot / 12, r = slot - sb2 * 12, G = r / 3, s = r - G * 3, u = s * 4 + sb2;
    bls[slot] = (u < HID) ? bias[G * HID + u] * gscale(G) : 0.f;
  }
  float Whr[HID][12];
  #pragma unroll
  for (int j = 0; j < 12; ++j) {
    const int G = j / 3, s = j - G * 3, u = s * 4 + sub;
    #pragma unroll
    for (int k = 0; k < HID; ++k)
      Whr[k][j] = (u < HID) ? Wh[k * GATES + G * HID + u] * gscale(G) : 0.f;
  }
  __syncthreads();
  float cst[3] = {0.f, 0.f, 0.f};
  float h[HID];
  #pragma unroll
  for (int k = 0; k < HID; ++k) h[k] = 0.f;
  float bb[12];
  #pragma unroll
  for (int j = 0; j < 12; ++j) bb[j] = bls[sub * 12 + j];
  const int* xrow = xs + lb * SEQ;
  float4 e0, e1, e2, e3, e4;
  {
    int row = xrow[0];
    const float4* q = (const float4*)(emb + (size_t)row * EMB);
    e0 = q[0]; e1 = q[1]; e2 = q[2]; e3 = q[3]; e4 = q[4];
  }
  #pragma unroll 1
  for (int t = 0; t < SEQ; ++t) {
    float e[EMB] = {e0.x,e0.y,e0.z,e0.w, e1.x,e1.y,e1.z,e1.w, e2.x,e2.y,e2.z,e2.w,
                    e3.x,e3.y,e3.z,e3.w, e4.x,e4.y,e4.z,e4.w};
    float z[12];
    #pragma unroll
    for (int j = 0; j < 12; ++j) z[j] = bb[j];
    #pragma unroll
    for (int k = 0; k < EMB; ++k)
      #pragma unroll
      for (int j = 0; j < 12; ++j)
        z[j] = fmaf(e[k], Wxl[k * 48 + sub * 12 + j], z[j]);
    if (t + 1 < SEQ) {
      int row = xrow[t + 1];
      const float4* q = (const float4*)(emb + (size_t)row * EMB);
      e0 = q[0]; e1 = q[1]; e2 = q[2]; e3 = q[3]; e4 = q[4];
    }
    #pragma unroll
    for (int k = 0; k < HID; ++k)
      #pragma unroll
      for (int j = 0; j < 12; ++j)
        z[j] = fmaf(h[k], Whr[k][j], z[j]);
    float hl[3];
    #pragma unroll
    for (int s = 0; s < 3; ++s) {
      float Ei = exp2_f(z[s]), Ef = exp2_f(z[s+3]);
      float Ec = exp2_f(fminf(z[s+6], 60.f)), Eo = exp2_f(z[s+9]);
      float f  = rcp_f(1.f + Ef);
      float ig = (1.f - Ec) * rcp_f((1.f + Ei) * (1.f + Ec));
      cst[s] = fmaf(f, cst[s], ig);
      float Et = exp2_f(fminf(-2.885390081777927f * cst[s], 60.f));
      hl[s] = (1.f - Et) * rcp_f((1.f + Eo) * (1.f + Et));
    }
    h[0] = qb<0x00>(hl[0]); h[1] = qb<0x55>(hl[0]); h[2] = qb<0xAA>(hl[0]); h[3] = qb<0xFF>(hl[0]);
    h[4] = qb<0x00>(hl[1]); h[5] = qb<0x55>(hl[1]); h[6] = qb<0xAA>(hl[1]); h[7] = qb<0xFF>(hl[1]);
    h[8] = qb<0x00>(hl[2]); h[9] = qb<0x55>(hl[2]);
  }
  #pragma unroll
  for (int s = 0; s < 4; ++s) {
    int j = s * 4 + sub;
    if (j < NLAB) {
      float acc = bd[j];
      #pragma unroll
      for (int k = 0; k < HID; ++k)
        acc = fmaf(h[k], Wd[k * NLAB + j], acc);
      out[(size_t)(b0 + lb) * NLAB + j] = acc;
    }
  }
}

extern "C" void kernel_launch(void* const* d_in, const int* in_sizes, int n_in,
                              void* d_out, int out_size, void* d_ws, size_t ws_size,
                              hipStream_t stream) {
  (void)in_sizes; (void)n_in; (void)out_size;
  const int*   x    = (const int*)  d_in[0];
  const float* emb  = (const float*)d_in[1];
  const float* Wx   = (const float*)d_in[2];
  const float* Wh   = (const float*)d_in[3];
  const float* bias = (const float*)d_in[4];
  const float* Wd   = (const float*)d_in[5];
  const float* bd   = (const float*)d_in[6];
  float* out = (float*)d_out;

  const size_t pbytes = (size_t)VOCAB * PROWH * sizeof(__half);   // 8 MB
  if (ws_size >= pbytes) {
    __half* P = (__half*)d_ws;
    hipLaunchKernelGGL(proj_kernel_h, dim3((VOCAB + 31) / 32), dim3(256), 0, stream,
                       emb, Wx, bias, P);
    hipLaunchKernelGGL(rnn16_kernel, dim3(BATCH / 16), dim3(256), 0, stream,
                       x, P, Wh, Wd, bd, out);
  } else {
    hipLaunchKernelGGL(rnn_kernel_fb, dim3(BATCH / 64), dim3(256), 0, stream,
                       x, emb, Wx, Wh, bias, Wd, bd, out);
  }
}

// Round 10
// 66.096 us; speedup vs baseline: 1.1173x; 1.1173x over previous
//
#include <hip/hip_runtime.h>
#include <hip/hip_fp16.h>

#define VOCAB 100000
#define EMB   20
#define HID   10
#define SEQ   100
#define NLAB  15
#define BATCH 16384
#define GATES 40
#define PROWH 40   // halfs/row, slot = u*4+G; lane u reads b64 @ half-offset 4u
#define EPB   24   // elements per block (4 waves x 6)

__device__ __forceinline__ float exp2_f(float x){ float r; asm("v_exp_f32 %0, %1" : "=v"(r) : "v"(x)); return r; }
__device__ __forceinline__ float rcp_f(float x){ float r; asm("v_rcp_f32 %0, %1" : "=v"(r) : "v"(x)); return r; }

// Gate scales folded into P/Wtab: sigmoid(x)=rcp(1+exp2(-log2e*x)),
// tanh(x)=(1-E)/(1+E), E=exp2(-2log2e*x). c-gate scale -2log2e, others -log2e.
__device__ __host__ __forceinline__ constexpr float gscale(int G){
  return (G == 2) ? -2.885390081777927f : -1.442695040888963f;
}

template<int CTRL>
__device__ __forceinline__ float qb(float x){
  return __int_as_float(__builtin_amdgcn_mov_dpp(__float_as_int(x), CTRL, 0xF, 0xF, true));
}

// -------- P = fp16( (embed @ Wx + b) * gate_scale ), row = 40 halfs, slot = u*4+G (r8, proven)
__global__ __launch_bounds__(256)
void proj_kernel_h(const float* __restrict__ emb, const float* __restrict__ Wx,
                   const float* __restrict__ bias, __half* __restrict__ P)
{
  __shared__ float Wxl[EMB * GATES];   // [k][slot], slot = u*4+G
  __shared__ float bl[GATES];
  const int tid = threadIdx.x;
  for (int i = tid; i < EMB * GATES; i += 256) {
    int k = i / GATES, slot = i - k * GATES;
    int u = slot >> 2, G = slot & 3;
    Wxl[i] = Wx[k * GATES + G * HID + u] * gscale(G);
  }
  if (tid < GATES) {
    int u = tid >> 2, G = tid & 3;
    bl[tid] = bias[G * HID + u] * gscale(G);
  }
  __syncthreads();

  const int v   = blockIdx.x * 32 + (tid >> 3);
  const int sub = tid & 7;
  if (v >= VOCAB) return;

  const float4* er = (const float4*)(emb + (size_t)v * EMB);
  float4 e0 = er[0], e1 = er[1], e2 = er[2], e3 = er[3], e4 = er[4];
  float e[EMB] = {e0.x,e0.y,e0.z,e0.w, e1.x,e1.y,e1.z,e1.w, e2.x,e2.y,e2.z,e2.w,
                  e3.x,e3.y,e3.z,e3.w, e4.x,e4.y,e4.z,e4.w};

  int sl[5] = {4*sub, 4*sub+1, 4*sub+2, 4*sub+3, 32+sub};
  float acc[5];
  #pragma unroll
  for (int c = 0; c < 5; ++c) acc[c] = bl[sl[c]];
  #pragma unroll
  for (int k = 0; k < EMB; ++k)
    #pragma unroll
    for (int c = 0; c < 5; ++c)
      acc[c] = fmaf(e[k], Wxl[k * GATES + sl[c]], acc[c]);

  union { __half h[4]; uint2 u2; } um;
  #pragma unroll
  for (int c = 0; c < 4; ++c) um.h[c] = __float2half(acc[c]);
  *(uint2*)(P + (size_t)v * PROWH + 4 * sub) = um.u2;
  P[(size_t)v * PROWH + 32 + sub] = __float2half(acc[4]);
}

// -------- Wtab[u][k][G] = Wh[k][G*10+u] * gscale(G)  (400 f32; lane u reads 10 float4)
__global__ __launch_bounds__(256)
void wtab_kernel(const float* __restrict__ Wh, float* __restrict__ Wtab)
{
  int i = blockIdx.x * 256 + threadIdx.x;
  if (i >= HID * HID * 4) return;
  int u = i / 40, r = i - u * 40, k = r >> 2, G = r & 3;
  Wtab[i] = Wh[k * GATES + G * HID + u] * gscale(G);
}

// -------- 10-lane-per-element LSTM: 6 elements/wave, lane u owns unit u entirely.
// z fully lane-local (4 gates = one b64 fp16 P-load + 40 f32 FMA); only h (10 f32)
// exchanged via a wave-private LDS row (same wave -> no barrier).
__global__ __launch_bounds__(256, 2)
void rnn10_kernel(const int* __restrict__ x, const __half* __restrict__ P,
                  const float* __restrict__ Wtab, const float* __restrict__ Wd,
                  const float* __restrict__ bd, float* __restrict__ out)
{
  __shared__ int xs[EPB * SEQ];                      // 9600 B
  __shared__ __align__(16) float hbuf[4][7][20];     // [wave][elem 0..5 + junk 6][10 h + pad]

  const int tid  = threadIdx.x;
  const int w    = tid >> 6;           // wave 0..3
  const int lane = tid & 63;
  const int el   = lane / 10;          // 0..5 real, 6 = junk (lanes 60-63)
  const int u    = lane - el * 10;     // unit 0..9 (junk lanes: 0..3)
  const int b0   = blockIdx.x * EPB;

  // stage tokens (rows beyond BATCH -> token 0)
  const int nrows = (BATCH - b0 < EPB) ? (BATCH - b0) : EPB;
  for (int i = tid; i < EPB * SEQ; i += 256) {
    int r = i / SEQ;
    xs[i] = (r < nrows) ? x[(size_t)b0 * SEQ + i] : 0;
  }

  // per-lane recurrent weights: 10 float4 (u-major, gate-scaled). If the
  // allocator re-sinks these, it's 10 b128 L1-hits/step (bounded), not 30-50.
  float4 wq[HID];
  #pragma unroll
  for (int k = 0; k < HID; ++k)
    wq[k] = *(const float4*)(Wtab + u * 40 + k * 4);

  __syncthreads();

  const int eidx = w * 6 + el;                       // block-local element (junk: 24..27)
  const int erow = (eidx < EPB) ? eidx : EPB - 1;    // clamp junk lanes' xs row
  const int* xrow = xs + erow * SEQ;
  float* hrow = hbuf[w][el];
  const bool act = (el < 6) && (b0 + eidx < BATCH);

  float c = 0.f;
  float h[HID];
  #pragma unroll
  for (int k = 0; k < HID; ++k) h[k] = 0.f;

  uint2 mA, mB, mC;
  auto ldrow = [&](uint2& m, int t) {
    int tt = t < SEQ ? t : SEQ - 1;
    int row = xrow[tt];
    m = *(const uint2*)(P + (size_t)row * PROWH + 4 * u);   // this unit's i,f,c,o
  };
  ldrow(mA, 0); ldrow(mB, 1); ldrow(mC, 2);

  auto step = [&](uint2& m, int t) {
    float2 g01 = __half22float2(*(const __half2*)&m.x);
    float2 g23 = __half22float2(*(const __half2*)&m.y);
    float zi = g01.x, zf = g01.y, zc = g23.x, zo = g23.y;
    ldrow(m, t + 3);                   // depth-3 prefetch

    #pragma unroll
    for (int k = 0; k < HID; ++k) {
      zi = fmaf(h[k], wq[k].x, zi);
      zf = fmaf(h[k], wq[k].y, zf);
      zc = fmaf(h[k], wq[k].z, zc);
      zo = fmaf(h[k], wq[k].w, zo);
    }

    // one activation chain per lane (algorithmic minimum: 5 exp2 + 3 rcp)
    float Ei = exp2_f(zi);
    float Ef = exp2_f(zf);
    float Ec = exp2_f(fminf(zc, 60.f));
    float Eo = exp2_f(zo);
    float f  = rcp_f(1.f + Ef);
    float ig = (1.f - Ec) * rcp_f((1.f + Ei) * (1.f + Ec));   // sigmoid(i)*tanh(c~)
    c = fmaf(f, c, ig);                                        // c = f*c + i*g
    float Et = exp2_f(fminf(-2.885390081777927f * c, 60.f));
    float hm = (1.f - Et) * rcp_f((1.f + Eo) * (1.f + Et));    // h = o*tanh(c)

    // exchange h within the element's 10 lanes (wave-private LDS row, no barrier)
    hrow[u] = hm;
    float4 a = *(const float4*)(hrow);
    float4 b = *(const float4*)(hrow + 4);
    float2 d = *(const float2*)(hrow + 8);
    h[0] = a.x; h[1] = a.y; h[2] = a.z; h[3] = a.w;
    h[4] = b.x; h[5] = b.y; h[6] = b.z; h[7] = b.w;
    h[8] = d.x; h[9] = d.y;
  };

  #pragma unroll 1
  for (int t = 0; t < SEQ - 1; t += 3) {   // 33 triples: t = 0..98
    step(mA, t);
    step(mB, t + 1);
    step(mC, t + 2);
  }
  step(mA, SEQ - 1);                       // t = 99

  // dense head: lane u computes logits u and 10+u
  if (act) {
    #pragma unroll
    for (int s = 0; s < 2; ++s) {
      int j = u + 10 * s;
      if (j < NLAB) {
        float acc = bd[j];
        #pragma unroll
        for (int k = 0; k < HID; ++k)
          acc = fmaf(h[k], Wd[k * NLAB + j], acc);
        out[(size_t)(b0 + eidx) * NLAB + j] = acc;
      }
    }
  }
}

// -------- fallback (ws too small): 4-lane on-the-fly f32 path (proven)
__global__ __launch_bounds__(256, 1)
void rnn_kernel_fb(const int* __restrict__ x, const float* __restrict__ emb,
                   const float* __restrict__ Wx, const float* __restrict__ Wh,
                   const float* __restrict__ bias, const float* __restrict__ Wd,
                   const float* __restrict__ bd, float* __restrict__ out)
{
  __shared__ int   xs[64 * SEQ];
  __shared__ float Wxl[EMB * 48];
  __shared__ float bls[48];
  const int tid = threadIdx.x, lb = tid >> 2, sub = tid & 3, b0 = blockIdx.x * 64;
  for (int i = tid; i < 64 * SEQ; i += 256) xs[i] = x[(size_t)b0 * SEQ + i];
  for (int i = tid; i < EMB * 48; i += 256) {
    int k = i / 48, slot = i - k * 48;
    int sb2 = slot / 12, r = slot - sb2 * 12, G = r / 3, s = r - G * 3, u = s * 4 + sb2;
    Wxl[i] = (u < HID) ? Wx[k * GATES + G * HID + u] * gscale(G) : 0.f;
  }
  if (tid < 48) {
    int slot = tid, sb2 = slot / 12, r = slot - sb2 * 12, G = r / 3, s = r - G * 3, u = s * 4 + sb2;
    bls[slot] = (u < HID) ? bias[G * HID + u] * gscale(G) : 0.f;
  }
  float Whr[HID][12];
  #pragma unroll
  for (int j = 0; j < 12; ++j) {
    const int G = j / 3, s = j - G * 3, u = s * 4 + sub;
    #pragma unroll
    for (int k = 0; k < HID; ++k)
      Whr[k][j] = (u < HID) ? Wh[k * GATES + G * HID + u] * gscale(G) : 0.f;
  }
  __syncthreads();
  float cst[3] = {0.f, 0.f, 0.f};
  float h[HID];
  #pragma unroll
  for (int k = 0; k < HID; ++k) h[k] = 0.f;
  float bb[12];
  #pragma unroll
  for (int j = 0; j < 12; ++j) bb[j] = bls[sub * 12 + j];
  const int* xrow = xs + lb * SEQ;
  float4 e0, e1, e2, e3, e4;
  {
    int row = xrow[0];
    const float4* q = (const float4*)(emb + (size_t)row * EMB);
    e0 = q[0]; e1 = q[1]; e2 = q[2]; e3 = q[3]; e4 = q[4];
  }
  #pragma unroll 1
  for (int t = 0; t < SEQ; ++t) {
    float e[EMB] = {e0.x,e0.y,e0.z,e0.w, e1.x,e1.y,e1.z,e1.w, e2.x,e2.y,e2.z,e2.w,
                    e3.x,e3.y,e3.z,e3.w, e4.x,e4.y,e4.z,e4.w};
    float z[12];
    #pragma unroll
    for (int j = 0; j < 12; ++j) z[j] = bb[j];
    #pragma unroll
    for (int k = 0; k < EMB; ++k)
      #pragma unroll
      for (int j = 0; j < 12; ++j)
        z[j] = fmaf(e[k], Wxl[k * 48 + sub * 12 + j], z[j]);
    if (t + 1 < SEQ) {
      int row = xrow[t + 1];
      const float4* q = (const float4*)(emb + (size_t)row * EMB);
      e0 = q[0]; e1 = q[1]; e2 = q[2]; e3 = q[3]; e4 = q[4];
    }
    #pragma unroll
    for (int k = 0; k < HID; ++k)
      #pragma unroll
      for (int j = 0; j < 12; ++j)
        z[j] = fmaf(h[k], Whr[k][j], z[j]);
    float hl[3];
    #pragma unroll
    for (int s = 0; s < 3; ++s) {
      float Ei = exp2_f(z[s]), Ef = exp2_f(z[s+3]);
      float Ec = exp2_f(fminf(z[s+6], 60.f)), Eo = exp2_f(z[s+9]);
      float f  = rcp_f(1.f + Ef);
      float ig = (1.f - Ec) * rcp_f((1.f + Ei) * (1.f + Ec));
      cst[s] = fmaf(f, cst[s], ig);
      float Et = exp2_f(fminf(-2.885390081777927f * cst[s], 60.f));
      hl[s] = (1.f - Et) * rcp_f((1.f + Eo) * (1.f + Et));
    }
    h[0] = qb<0x00>(hl[0]); h[1] = qb<0x55>(hl[0]); h[2] = qb<0xAA>(hl[0]); h[3] = qb<0xFF>(hl[0]);
    h[4] = qb<0x00>(hl[1]); h[5] = qb<0x55>(hl[1]); h[6] = qb<0xAA>(hl[1]); h[7] = qb<0xFF>(hl[1]);
    h[8] = qb<0x00>(hl[2]); h[9] = qb<0x55>(hl[2]);
  }
  #pragma unroll
  for (int s = 0; s < 4; ++s) {
    int j = s * 4 + sub;
    if (j < NLAB) {
      float acc = bd[j];
      #pragma unroll
      for (int k = 0; k < HID; ++k)
        acc = fmaf(h[k], Wd[k * NLAB + j], acc);
      out[(size_t)(b0 + lb) * NLAB + j] = acc;
    }
  }
}

extern "C" void kernel_launch(void* const* d_in, const int* in_sizes, int n_in,
                              void* d_out, int out_size, void* d_ws, size_t ws_size,
                              hipStream_t stream) {
  (void)in_sizes; (void)n_in; (void)out_size;
  const int*   x    = (const int*)  d_in[0];
  const float* emb  = (const float*)d_in[1];
  const float* Wx   = (const float*)d_in[2];
  const float* Wh   = (const float*)d_in[3];
  const float* bias = (const float*)d_in[4];
  const float* Wd   = (const float*)d_in[5];
  const float* bd   = (const float*)d_in[6];
  float* out = (float*)d_out;

  const size_t pbytes  = (size_t)VOCAB * PROWH * sizeof(__half);        // 8 MB
  const size_t wt_off  = (pbytes + 255) & ~(size_t)255;
  const size_t need    = wt_off + (size_t)HID * HID * 4 * sizeof(float);
  if (ws_size >= need) {
    __half* P    = (__half*)d_ws;
    float*  Wtab = (float*)((char*)d_ws + wt_off);
    hipLaunchKernelGGL(proj_kernel_h, dim3((VOCAB + 31) / 32), dim3(256), 0, stream,
                       emb, Wx, bias, P);
    hipLaunchKernelGGL(wtab_kernel, dim3(2), dim3(256), 0, stream, Wh, Wtab);
    hipLaunchKernelGGL(rnn10_kernel, dim3((BATCH + EPB - 1) / EPB), dim3(256), 0, stream,
                       x, P, Wtab, Wd, bd, out);
  } else {
    hipLaunchKernelGGL(rnn_kernel_fb, dim3(BATCH / 64), dim3(256), 0, stream,
                       x, emb, Wx, Wh, bias, Wd, bd, out);
  }
}